// Round 10
// baseline (6092.796 us; speedup 1.0000x reference)
//
#include <hip/hip_runtime.h>
#include <cstdint>
#include <cstddef>

#define BATCH   4096
#define IN_DIM  1024
#define HID     16384
#define KSEL    32

// ---------------------------------------------------------------------------
// Kernel 1: encoder GEMM  C[B,H] = X[B,D] @ W_enc[H,D]^T + b_enc
// fp32. 64x256 tile, BK=32, 512 threads (8 waves x 8 rows), lane owns 4 cols
// {lane, +64, +128, +192}. A is WAVE-UNIFORM and loaded through the
// CONSTANT address space (AS4) -> backend selects s_load_dwordx4 (scalar
// pipe, zero VGPR) with COMPILER-managed SGPR allocation. B staged in LDS.
// ZERO inline asm in this kernel (see r9-r13 abort history).
//
// NUMERICS CONTRACT (do not change): per output element, fmaf over k in
// strictly ascending order with a single accumulator, then + bias. Top-k
// rank-32 boundary gaps are ~0.007; any reordering (MFMA bf16x3: absmax
// 4.31, or k-splitting) flips selections vs the np reference. MFMA unusable.
//
// HISTORY:
//  r5: 16x8 micro-tile spilled acc -> REGRESSED (1850->2600).
//  r6: 8x8, 4 blk/CU, A+B in LDS: 1830us, LDS-pipe-bound (1.0 B/FMA).
//  r7: A via vector global loads: compiler hoisted 64 loads, acc spilled,
//      WRITE_SIZE 8.5GB, 5100us. Per-lane vector-loading A in-loop with
//      unbounded scheduling is unfixable.
//  r8: A via s_load inline-asm block, 2 cols/lane: 1650us. No spill,
//      occ 87%, VALUBusy 79%. Excess ~1M cyc/SIMD = s->v movs.
//  r9/r10/r13: three aborts (GPU fault). Common factor: the 8-quad "=s"
//      s_load asm block under raised register pressure (tied FMA asm ops
//      in r9/r10; +24 VGPR at cap 64 in r13). Low-pressure r8/r12 passed.
//      CONCLUSION: the s_load asm block is fragile under pressure. BANNED
//      along with all inline asm in this kernel.
//  r12: r8 + bank swizzle fix: 2037us total. SQ_LDS_BANK_CONFLICT EXACTLY
//      unchanged (1.342e8 = 4cyc x 2^25 b128 reads) under two different
//      swizzles -> conflict cost is INTRINSIC to 64-lane b128 panel reads.
//      Stop optimizing that counter; it is priced in.
//  r15 (this): AS4 (constant addrspace) A-loads replace the asm block --
//      same s_load_dwordx4 selection, compiler-managed SGPRs, and the
//      compiler can fold SGPR scalars straight into v_fmac src0 (kills the
//      mov tax). 4 cols/lane (BN=256) amortizes A 4x and halves A re-reads
//      (FETCH pred. 1.5GB -> ~0.9GB). acc 32 + b 16 + addr ~60 VGPR fits
//      (512,8) cap 64. B tile 32KB LDS, 4 blocks/CU = 128KB.
// ---------------------------------------------------------------------------
#define BKK 32

typedef float f32x4_t __attribute__((ext_vector_type(4)));
typedef const __attribute__((address_space(4))) f32x4_t* cvec4_t;

__global__ __launch_bounds__(512, 8)
void enc_gemm(const float* __restrict__ X, const float* __restrict__ W,
              const float* __restrict__ bias, float* __restrict__ C)
{
    __shared__ __align__(16) float Bs[256 * BKK];   // 32 KB, row-major, swizzled

    const int bn = blockIdx.x;   // HID/256 = 64 (fast dim)
    const int bm = blockIdx.y;   // BATCH/64 = 64
    const int t  = threadIdx.x;  // 0..511
    const int lane = t & 63;
    const int wid  = t >> 6;     // 0..7: wave owns rows bm*64 + wid*8 .. +7

    float acc[8][4];
#pragma unroll
    for (int r = 0; r < 8; ++r)
#pragma unroll
        for (int j = 0; j < 4; ++j) acc[r][j] = 0.f;

    const float* Wb = W + (size_t)(bn * 256) * IN_DIM;

    // Wave-uniform A base (rows bm*64+wid*8 .. +7). readfirstlane marks it
    // uniform; the AS4 (constant) cast makes uniform loads select s_load.
    const unsigned rowByte = (unsigned)__builtin_amdgcn_readfirstlane(
        (int)((unsigned)(bm * 64 + wid * 8) * (unsigned)(IN_DIM * 4)));
    const __attribute__((address_space(4))) char* aBase =
        (const __attribute__((address_space(4))) char*)((const char*)X + rowByte);

    const int bswz = lane & 7;   // B-read swizzle key (row&7; +64k keeps it)
    const float* bRow0 = Bs + (size_t)lane * BKK;         // col = lane
    const float* bRow1 = Bs + (size_t)(lane + 64) * BKK;  // col = lane+64
    const float* bRow2 = Bs + (size_t)(lane + 128) * BKK; // col = lane+128
    const float* bRow3 = Bs + (size_t)(lane + 192) * BKK; // col = lane+192

    for (int k0 = 0; k0 < IN_DIM; k0 += BKK) {
        // ---- stage 256x32 B tile: 4 x 16B per thread (512 threads).
        // LDS slot s (16B) holds row m = s>>3, global chunk (s&7)^(m&7).
        // Lane-contiguous LDS dst satisfies wave-uniform-base + lane*16;
        // each 8-lane group reads one contiguous (permuted) 128B of global.
#pragma unroll
        for (int q = 0; q < 4; ++q) {
            const int s  = q * 512 + t;           // 0..2047
            const int m  = s >> 3;                // 0..255
            const int gc = (s & 7) ^ (m & 7);
            __builtin_amdgcn_global_load_lds(
                (const __attribute__((address_space(1))) void*)(Wb + (size_t)m * IN_DIM + k0 + gc * 4),
                (__attribute__((address_space(3))) void*)(Bs + s * 4), 16, 0, 0);
        }
        __syncthreads();   // drains vmcnt (global_load_lds) before reads

        // ---- compute: 8 groups of 4 consecutive k.
#pragma unroll
        for (int kq = 0; kq < 8; ++kq) {
            const float4 b0 = *(const float4*)(bRow0 + ((kq ^ bswz) * 4));
            const float4 b1 = *(const float4*)(bRow1 + ((kq ^ bswz) * 4));
            const float4 b2 = *(const float4*)(bRow2 + ((kq ^ bswz) * 4));
            const float4 b3 = *(const float4*)(bRow3 + ((kq ^ bswz) * 4));

            // A: 8 rows x 4 k via AS4 loads (uniform addr -> s_load_dwordx4,
            // SGPR dest, zero VGPR). Row stride = IN_DIM*4 B = 256 vec4s.
            cvec4_t ap = (cvec4_t)(aBase + (size_t)(k0 + kq * 4) * 4);
            const f32x4_t a0 = ap[0 * 256];
            const f32x4_t a1 = ap[1 * 256];
            const f32x4_t a2 = ap[2 * 256];
            const f32x4_t a3 = ap[3 * 256];
            const f32x4_t a4 = ap[4 * 256];
            const f32x4_t a5 = ap[5 * 256];
            const f32x4_t a6 = ap[6 * 256];
            const f32x4_t a7 = ap[7 * 256];

            // k ascending per output, x->y->z->w: bit-identical chain.
            // Plain fmaf; SGPR a-scalar folds into v_fmac src0.
#define ROW_FMA(AV, R)                                   \
            acc[R][0] = fmaf(AV.x, b0.x, acc[R][0]);     \
            acc[R][1] = fmaf(AV.x, b1.x, acc[R][1]);     \
            acc[R][2] = fmaf(AV.x, b2.x, acc[R][2]);     \
            acc[R][3] = fmaf(AV.x, b3.x, acc[R][3]);     \
            acc[R][0] = fmaf(AV.y, b0.y, acc[R][0]);     \
            acc[R][1] = fmaf(AV.y, b1.y, acc[R][1]);     \
            acc[R][2] = fmaf(AV.y, b2.y, acc[R][2]);     \
            acc[R][3] = fmaf(AV.y, b3.y, acc[R][3]);     \
            acc[R][0] = fmaf(AV.z, b0.z, acc[R][0]);     \
            acc[R][1] = fmaf(AV.z, b1.z, acc[R][1]);     \
            acc[R][2] = fmaf(AV.z, b2.z, acc[R][2]);     \
            acc[R][3] = fmaf(AV.z, b3.z, acc[R][3]);     \
            acc[R][0] = fmaf(AV.w, b0.w, acc[R][0]);     \
            acc[R][1] = fmaf(AV.w, b1.w, acc[R][1]);     \
            acc[R][2] = fmaf(AV.w, b2.w, acc[R][2]);     \
            acc[R][3] = fmaf(AV.w, b3.w, acc[R][3]);
            ROW_FMA(a0, 0) ROW_FMA(a1, 1) ROW_FMA(a2, 2) ROW_FMA(a3, 3)
            ROW_FMA(a4, 4) ROW_FMA(a5, 5) ROW_FMA(a6, 6) ROW_FMA(a7, 7)
#undef ROW_FMA
        }
        __syncthreads();
    }

    const int r0 = bm * 64 + wid * 8;
    const int c0 = bn * 256 + lane;
    float bv[4];
#pragma unroll
    for (int j = 0; j < 4; ++j) bv[j] = bias[c0 + j * 64];
#pragma unroll
    for (int r = 0; r < 8; ++r) {
        const size_t rowoff = (size_t)(r0 + r) * HID + c0;
#pragma unroll
        for (int j = 0; j < 4; ++j)
            C[rowoff + j * 64] = acc[r][j] + bv[j];
    }
}

// ---------------------------------------------------------------------------
// Kernel 2 (v4): per-row exact top-32 by |value|, 4-level radix select on
// abs bit pattern. Row cached in LDS (64 KB) -> global traffic = 1 read +
// 1 write. Suffix "scan" via wave shuffles (no LDS scan array / barriers).
// Levels: bits 30:23 (256), 22:15 (256), 14:7 (256), 6:0 (128).
// ---------------------------------------------------------------------------
__global__ __launch_bounds__(256)
void topk_rows(float* __restrict__ E, int* __restrict__ idx_out,
               float* __restrict__ val_out)
{
    const int row = blockIdx.x;
    float* p = E + (size_t)row * HID;
    const int t    = threadIdx.x;
    const int lane = t & 63;
    const int wid  = t >> 6;

    __shared__ __align__(16) float row_s[HID];   // 64 KB row cache
    __shared__ unsigned h8[8][257];              // lvl-0 privatized hists
    __shared__ unsigned hist[256];
    __shared__ unsigned wsum[4];
    __shared__ unsigned s_prefix;
    __shared__ int s_rank, s_eq, s_cnt;

    // async-load the whole row into LDS (lane-contiguous 16B chunks)
#pragma unroll
    for (int c = 0; c < 16; ++c) {
        const int s = c * 256 + t;
        __builtin_amdgcn_global_load_lds(
            (const __attribute__((address_space(1))) void*)(p + (size_t)s * 4),
            (__attribute__((address_space(3))) void*)(row_s + s * 4), 16, 0, 0);
    }
    for (int i = t; i < 8 * 257; i += 256) ((unsigned*)h8)[i] = 0u;
    if (t == 0) { s_rank = KSEL; s_prefix = 0u; s_eq = 0; s_cnt = 0; }
    __syncthreads();

    // ---- level 0: exponent-byte histogram into 8 privatized copies
    unsigned* myh = h8[t & 7];
#pragma unroll
    for (int c = 0; c < 16; ++c) {
        const float4 v = *(const float4*)(row_s + (c * 256 + t) * 4);
        const float vv[4] = {v.x, v.y, v.z, v.w};
#pragma unroll
        for (int j = 0; j < 4; ++j)
            atomicAdd(&myh[(__float_as_uint(vv[j]) & 0x7FFFFFFFu) >> 23], 1u);
    }
    __syncthreads();

    const int psh_arr[4]  = {31, 23, 15, 7};
    const int sh_arr[4]   = {23, 15, 7, 0};
    const unsigned msk[4] = {255u, 255u, 255u, 127u};
    const int bits_arr[4] = {8, 8, 8, 7};

#pragma unroll
    for (int lvl = 0; lvl < 4; ++lvl) {
        const int r = s_rank;
        const unsigned pfx = s_prefix;

        unsigned mycnt;
        if (lvl == 0) {
            unsigned m = 0;
#pragma unroll
            for (int c = 0; c < 8; ++c) m += h8[c][t];
            mycnt = m;                       // own bin, no barrier needed
        } else {
            hist[t] = 0u;
            __syncthreads();
            const int psh = psh_arr[lvl];
            const int sh  = sh_arr[lvl];
#pragma unroll
            for (int c = 0; c < 16; ++c) {
                const float4 v = *(const float4*)(row_s + (c * 256 + t) * 4);
                const float vv[4] = {v.x, v.y, v.z, v.w};
#pragma unroll
                for (int j = 0; j < 4; ++j) {
                    const unsigned k = __float_as_uint(vv[j]) & 0x7FFFFFFFu;
                    if ((k >> psh) == pfx)   // few matches: contention trivial
                        atomicAdd(&hist[(k >> sh) & msk[lvl]], 1u);
                }
            }
            __syncthreads();
            mycnt = hist[t];
        }

        // wave-level inclusive suffix scan of bin counts (bin index = t)
        unsigned sv = mycnt;
#pragma unroll
        for (int off = 1; off < 64; off <<= 1) {
            const unsigned u = __shfl_down(sv, off, 64);
            sv += (lane + off < 64) ? u : 0u;
        }
        if (lane == 0) wsum[wid] = sv;       // this wave's 64-bin total
        __syncthreads();
        unsigned above = 0;
        for (int ww = wid + 1; ww < 4; ++ww) above += wsum[ww];
        const unsigned suff  = sv + above;   // sum of bins >= t
        const unsigned suffn = suff - mycnt; // sum of bins >  t
        if (suff >= (unsigned)r && suffn < (unsigned)r) {  // exactly one thread
            s_rank   = r - (int)suffn;
            s_prefix = (pfx << bits_arr[lvl]) | (unsigned)t;
        }
        __syncthreads();
    }

    const unsigned vkey = s_prefix;   // exact 31-bit abs key of the 32nd largest
    const int eq_need   = s_rank;     // how many ==vkey elements to keep (>=1)

    // ---- final: mask from LDS, write global row + compact (idx,val) lists
#pragma unroll
    for (int c = 0; c < 16; ++c) {
        const int i0 = (c * 256 + t) * 4;
        const float4 v = *(const float4*)(row_s + i0);
        float vv[4] = {v.x, v.y, v.z, v.w};
#pragma unroll
        for (int j = 0; j < 4; ++j) {
            const unsigned k = __float_as_uint(vv[j]) & 0x7FFFFFFFu;
            bool keep = false;
            if (k > vkey) keep = true;
            else if (k == vkey) {
                const int slot = atomicAdd(&s_eq, 1);
                if (slot < eq_need) keep = true;
            }
            if (keep) {
                const int ls = atomicAdd(&s_cnt, 1);
                idx_out[row * KSEL + ls] = i0 + j;
                val_out[row * KSEL + ls] = vv[j];
            } else {
                vv[j] = 0.f;
            }
        }
        float4 o; o.x = vv[0]; o.y = vv[1]; o.z = vv[2]; o.w = vv[3];
        *(float4*)(p + i0) = o;
    }
}

// ---------------------------------------------------------------------------
// Kernel 3: transpose W_dec [1024,16384] -> WdT [16384,1024] (ws scratch)
// ---------------------------------------------------------------------------
__global__ __launch_bounds__(256)
void transpose_wdec(const float* __restrict__ Wd, float* __restrict__ WdT)
{
    __shared__ float tile[32][33];
    const int bx = blockIdx.x;
    const int by = blockIdx.y;
    const int t  = threadIdx.x;
    const int lx = t & 31, ly = t >> 5;
#pragma unroll
    for (int r = 0; r < 32; r += 8)
        tile[ly + r][lx] = Wd[(size_t)(by * 32 + ly + r) * HID + bx * 32 + lx];
    __syncthreads();
#pragma unroll
    for (int r = 0; r < 32; r += 8)
        WdT[(size_t)(bx * 32 + ly + r) * IN_DIM + by * 32 + lx] = tile[lx][ly + r];
}

// ---------------------------------------------------------------------------
// Kernel 4: sparse decode  decoded[b,:] = sum_i val_i * WdT[idx_i,:] + b_dec
// ---------------------------------------------------------------------------
__global__ __launch_bounds__(256)
void decode_rows(const float* __restrict__ WdT, const float* __restrict__ bd,
                 const int* __restrict__ idxs, const float* __restrict__ vals,
                 float* __restrict__ out)
{
    const int row = blockIdx.x;
    const int d   = threadIdx.x * 4;
    float4 acc = *(const float4*)(bd + d);
    for (int i = 0; i < KSEL; ++i) {
        const int   j = idxs[row * KSEL + i];
        const float v = vals[row * KSEL + i];
        const float4 w = *(const float4*)(WdT + (size_t)j * IN_DIM + d);
        acc.x = fmaf(v, w.x, acc.x);
        acc.y = fmaf(v, w.y, acc.y);
        acc.z = fmaf(v, w.z, acc.z);
        acc.w = fmaf(v, w.w, acc.w);
    }
    *(float4*)(out + (size_t)row * IN_DIM + d) = acc;
}

__global__ __launch_bounds__(256)
void decode_rows_noT(const float* __restrict__ Wd, const float* __restrict__ bd,
                     const int* __restrict__ idxs, const float* __restrict__ vals,
                     float* __restrict__ out)
{
    const int row = blockIdx.x;
    const int d0  = threadIdx.x * 4;
    float acc[4];
#pragma unroll
    for (int q = 0; q < 4; ++q) acc[q] = bd[d0 + q];
    for (int i = 0; i < KSEL; ++i) {
        const int   j = idxs[row * KSEL + i];
        const float v = vals[row * KSEL + i];
#pragma unroll
        for (int q = 0; q < 4; ++q)
            acc[q] = fmaf(v, Wd[(size_t)(d0 + q) * HID + j], acc[q]);
    }
#pragma unroll
    for (int q = 0; q < 4; ++q) out[(size_t)row * IN_DIM + d0 + q] = acc[q];
}

// ---------------------------------------------------------------------------
extern "C" void kernel_launch(void* const* d_in, const int* in_sizes, int n_in,
                              void* d_out, int out_size, void* d_ws, size_t ws_size,
                              hipStream_t stream)
{
    const float* x     = (const float*)d_in[0];
    const float* W_enc = (const float*)d_in[1];
    const float* b_enc = (const float*)d_in[2];
    const float* W_dec = (const float*)d_in[3];
    const float* b_dec = (const float*)d_in[4];

    float* out     = (float*)d_out;
    float* sparse  = out;                                // [4096][16384]
    float* decoded = out + (size_t)BATCH * HID;          // [4096][1024]

    // ws layout: [idx list 512KB][val list 512KB][WdT 64MB]
    const size_t list_bytes = (size_t)BATCH * KSEL * 4;
    const size_t wdt_bytes  = (size_t)HID * IN_DIM * 4;
    int*   idx_l = (int*)d_ws;
    float* val_l = (float*)((char*)d_ws + list_bytes);
    float* WdT   = (float*)((char*)d_ws + 2 * list_bytes);
    const bool have_wdt = ws_size >= 2 * list_bytes + wdt_bytes;

    enc_gemm<<<dim3(HID / 256, BATCH / 64), 512, 0, stream>>>(x, W_enc, b_enc, sparse);

    topk_rows<<<BATCH, 256, 0, stream>>>(sparse, idx_l, val_l);

    if (have_wdt) {
        transpose_wdec<<<dim3(HID / 32, IN_DIM / 32), 256, 0, stream>>>(W_dec, WdT);
        decode_rows<<<BATCH, 256, 0, stream>>>(WdT, b_dec, idx_l, val_l, decoded);
    } else {
        decode_rows_noT<<<BATCH, 256, 0, stream>>>(W_dec, b_dec, idx_l, val_l, decoded);
    }
}

// Round 12
// 2098.366 us; speedup vs baseline: 2.9036x; 2.9036x over previous
//
#include <hip/hip_runtime.h>
#include <cstdint>
#include <cstddef>

#define BATCH   4096
#define IN_DIM  1024
#define HID     16384
#define KSEL    32

// ---------------------------------------------------------------------------
// Kernel 1: encoder GEMM  C[B,H] = X[B,D] @ W_enc[H,D]^T + b_enc
// fp32. 64x128 tile, BK=32, 512 threads (8 waves x 8 rows), lane owns 2 cols.
// A is WAVE-UNIFORM -> s_load_dwordx4 into SGPRs (scalar pipe); only B in
// LDS. FMAs in plain C (fmaf).
//
// THIS IS THE PROVEN LOCAL OPTIMUM (r12: 2037us total, enc 1650us).
// FIVE deviations from this exact structure faulted or spilled:
//   r9/r10: FMA inline asm (VOP2/VOP3)            -> GPU fault
//   r13:    4 cols/lane (+24 VGPR at cap 64)       -> GPU fault
//   r15:    AS4 constant-space A-loads (no asm)    -> 12.8GB scratch spill
//   r16:    LDS double-buffer around the asm block -> GPU fault
//   r5/r7:  bigger acc / vector A-loads            -> scratch spill
// The s_load asm block is BOTH load-bearing (r15: compiler can't scalarize
// A itself) AND brittle (any surrounding-context change faults). Do not
// modify enc_gemm further; remaining gap to the 874us FMA floor is
// structural (s->v mov tax ~47%, barrier bubbles ~20%, intrinsic b128
// bank tax 1.342e8 cyc = 4cyc x 2^25 reads, identical under two swizzles).
//
// NUMERICS CONTRACT (do not change): per output element, fmaf over k in
// strictly ascending order with a single accumulator, then + bias. Top-k
// rank-32 boundary gaps are ~0.007; any reordering (MFMA bf16x3: absmax
// 4.31, or k-splitting) flips selections vs the np reference. MFMA unusable.
// ---------------------------------------------------------------------------
#define BKK 32

typedef float f32x4_t __attribute__((ext_vector_type(4)));

__global__ __launch_bounds__(512, 8)
void enc_gemm(const float* __restrict__ X, const float* __restrict__ W,
              const float* __restrict__ bias, float* __restrict__ C)
{
    __shared__ __align__(16) float Bs[128 * BKK];   // 16 KB, row-major, swizzled

    const int bn = blockIdx.x;   // HID/128 = 128 (fast dim)
    const int bm = blockIdx.y;   // BATCH/64 = 64
    const int t  = threadIdx.x;  // 0..511
    const int lane = t & 63;
    const int wid  = t >> 6;     // 0..7: wave owns rows bm*64 + wid*8 .. +7

    float acc[8][2];
#pragma unroll
    for (int r = 0; r < 8; ++r) { acc[r][0] = 0.f; acc[r][1] = 0.f; }

    const float* Wb = W + (size_t)(bn * 128) * IN_DIM;

    // Wave-uniform A base (rows bm*64+wid*8 .. +7), forced to SGPR.
    const unsigned rowByte = (unsigned)__builtin_amdgcn_readfirstlane(
        (int)((unsigned)(bm * 64 + wid * 8) * (unsigned)(IN_DIM * 4)));
    const char* aBase = (const char*)X + rowByte;

    const int bswz = lane & 7;   // B-read swizzle key (row&7; (lane+64)&7 same)
    const float* bRow0 = Bs + (size_t)lane * BKK;        // col = lane
    const float* bRow1 = Bs + (size_t)(lane + 64) * BKK; // col = lane+64

    for (int k0 = 0; k0 < IN_DIM; k0 += BKK) {
        // ---- stage 128x32 B tile: 2 x 16B per thread (512 threads).
        // LDS slot s (16B) holds row m = s>>3, global chunk (s&7)^(m&7).
        // Read of logical chunk kq of row m is at physical chunk kq^(m&7):
        // lanes 0..7 read 8 distinct chunks. Lane-contiguous LDS dst
        // satisfies wave-uniform-base + lane*16; each 8-lane group reads
        // one contiguous (permuted) 128B of global -> fully coalesced.
#pragma unroll
        for (int q = 0; q < 2; ++q) {
            const int s  = q * 512 + t;           // 0..1023
            const int m  = s >> 3;                // 0..127
            const int gc = (s & 7) ^ (m & 7);
            __builtin_amdgcn_global_load_lds(
                (const __attribute__((address_space(1))) void*)(Wb + (size_t)m * IN_DIM + k0 + gc * 4),
                (__attribute__((address_space(3))) void*)(Bs + s * 4), 16, 0, 0);
        }
        __syncthreads();   // drains vmcnt (global_load_lds) before reads

        // ---- compute: 8 groups of 4 consecutive k.
#pragma unroll
        for (int kq = 0; kq < 8; ++kq) {
            const float4 b0 = *(const float4*)(bRow0 + ((kq ^ bswz) * 4));
            const float4 b1 = *(const float4*)(bRow1 + ((kq ^ bswz) * 4));

            // A: 8 rows x 4 k into SGPRs. One volatile asm block per kq:
            // bounded SGPR live range (32), cannot be hoisted across kq.
            // EXACT r8/r12 block — do not alter (pressure-fragility).
            const char* apq = aBase + (size_t)(k0 + kq * 4) * 4;
            f32x4_t a0, a1, a2, a3, a4, a5, a6, a7;
            asm volatile(
                "s_load_dwordx4 %[r0], %[ap], 0x0\n\t"
                "s_load_dwordx4 %[r1], %[ap], 0x1000\n\t"
                "s_load_dwordx4 %[r2], %[ap], 0x2000\n\t"
                "s_load_dwordx4 %[r3], %[ap], 0x3000\n\t"
                "s_load_dwordx4 %[r4], %[ap], 0x4000\n\t"
                "s_load_dwordx4 %[r5], %[ap], 0x5000\n\t"
                "s_load_dwordx4 %[r6], %[ap], 0x6000\n\t"
                "s_load_dwordx4 %[r7], %[ap], 0x7000\n\t"
                "s_waitcnt lgkmcnt(0)"
                : [r0]"=s"(a0), [r1]"=s"(a1), [r2]"=s"(a2), [r3]"=s"(a3),
                  [r4]"=s"(a4), [r5]"=s"(a5), [r6]"=s"(a6), [r7]"=s"(a7)
                : [ap]"s"(apq));

            // k ascending per output, x->y->z->w: bit-identical chain.
            // Plain fmaf (NO inline asm here — r9/r10 lesson).
#define ROW_FMA(AV, R)                                   \
            acc[R][0] = fmaf(AV.x, b0.x, acc[R][0]);     \
            acc[R][1] = fmaf(AV.x, b1.x, acc[R][1]);     \
            acc[R][0] = fmaf(AV.y, b0.y, acc[R][0]);     \
            acc[R][1] = fmaf(AV.y, b1.y, acc[R][1]);     \
            acc[R][0] = fmaf(AV.z, b0.z, acc[R][0]);     \
            acc[R][1] = fmaf(AV.z, b1.z, acc[R][1]);     \
            acc[R][0] = fmaf(AV.w, b0.w, acc[R][0]);     \
            acc[R][1] = fmaf(AV.w, b1.w, acc[R][1]);
            ROW_FMA(a0, 0) ROW_FMA(a1, 1) ROW_FMA(a2, 2) ROW_FMA(a3, 3)
            ROW_FMA(a4, 4) ROW_FMA(a5, 5) ROW_FMA(a6, 6) ROW_FMA(a7, 7)
#undef ROW_FMA
        }
        __syncthreads();
    }

    const int r0 = bm * 64 + wid * 8;
    const int c0 = bn * 128 + lane;
    const float bv0 = bias[c0];
    const float bv1 = bias[c0 + 64];
#pragma unroll
    for (int r = 0; r < 8; ++r) {
        C[(size_t)(r0 + r) * HID + c0]      = acc[r][0] + bv0;
        C[(size_t)(r0 + r) * HID + c0 + 64] = acc[r][1] + bv1;
    }
}

// ---------------------------------------------------------------------------
// Kernel 2 (v4): per-row exact top-32 by |value|, 4-level radix select on
// abs bit pattern. Row cached in LDS (64 KB) -> global traffic = 1 read +
// 1 write. Suffix "scan" via wave shuffles (no LDS scan array / barriers).
// Levels: bits 30:23 (256), 22:15 (256), 14:7 (256), 6:0 (128).
// ---------------------------------------------------------------------------
__global__ __launch_bounds__(256)
void topk_rows(float* __restrict__ E, int* __restrict__ idx_out,
               float* __restrict__ val_out)
{
    const int row = blockIdx.x;
    float* p = E + (size_t)row * HID;
    const int t    = threadIdx.x;
    const int lane = t & 63;
    const int wid  = t >> 6;

    __shared__ __align__(16) float row_s[HID];   // 64 KB row cache
    __shared__ unsigned h8[8][257];              // lvl-0 privatized hists
    __shared__ unsigned hist[256];
    __shared__ unsigned wsum[4];
    __shared__ unsigned s_prefix;
    __shared__ int s_rank, s_eq, s_cnt;

    // async-load the whole row into LDS (lane-contiguous 16B chunks)
#pragma unroll
    for (int c = 0; c < 16; ++c) {
        const int s = c * 256 + t;
        __builtin_amdgcn_global_load_lds(
            (const __attribute__((address_space(1))) void*)(p + (size_t)s * 4),
            (__attribute__((address_space(3))) void*)(row_s + s * 4), 16, 0, 0);
    }
    for (int i = t; i < 8 * 257; i += 256) ((unsigned*)h8)[i] = 0u;
    if (t == 0) { s_rank = KSEL; s_prefix = 0u; s_eq = 0; s_cnt = 0; }
    __syncthreads();

    // ---- level 0: exponent-byte histogram into 8 privatized copies
    unsigned* myh = h8[t & 7];
#pragma unroll
    for (int c = 0; c < 16; ++c) {
        const float4 v = *(const float4*)(row_s + (c * 256 + t) * 4);
        const float vv[4] = {v.x, v.y, v.z, v.w};
#pragma unroll
        for (int j = 0; j < 4; ++j)
            atomicAdd(&myh[(__float_as_uint(vv[j]) & 0x7FFFFFFFu) >> 23], 1u);
    }
    __syncthreads();

    const int psh_arr[4]  = {31, 23, 15, 7};
    const int sh_arr[4]   = {23, 15, 7, 0};
    const unsigned msk[4] = {255u, 255u, 255u, 127u};
    const int bits_arr[4] = {8, 8, 8, 7};

#pragma unroll
    for (int lvl = 0; lvl < 4; ++lvl) {
        const int r = s_rank;
        const unsigned pfx = s_prefix;

        unsigned mycnt;
        if (lvl == 0) {
            unsigned m = 0;
#pragma unroll
            for (int c = 0; c < 8; ++c) m += h8[c][t];
            mycnt = m;                       // own bin, no barrier needed
        } else {
            hist[t] = 0u;
            __syncthreads();
            const int psh = psh_arr[lvl];
            const int sh  = sh_arr[lvl];
#pragma unroll
            for (int c = 0; c < 16; ++c) {
                const float4 v = *(const float4*)(row_s + (c * 256 + t) * 4);
                const float vv[4] = {v.x, v.y, v.z, v.w};
#pragma unroll
                for (int j = 0; j < 4; ++j) {
                    const unsigned k = __float_as_uint(vv[j]) & 0x7FFFFFFFu;
                    if ((k >> psh) == pfx)   // few matches: contention trivial
                        atomicAdd(&hist[(k >> sh) & msk[lvl]], 1u);
                }
            }
            __syncthreads();
            mycnt = hist[t];
        }

        // wave-level inclusive suffix scan of bin counts (bin index = t)
        unsigned sv = mycnt;
#pragma unroll
        for (int off = 1; off < 64; off <<= 1) {
            const unsigned u = __shfl_down(sv, off, 64);
            sv += (lane + off < 64) ? u : 0u;
        }
        if (lane == 0) wsum[wid] = sv;       // this wave's 64-bin total
        __syncthreads();
        unsigned above = 0;
        for (int ww = wid + 1; ww < 4; ++ww) above += wsum[ww];
        const unsigned suff  = sv + above;   // sum of bins >= t
        const unsigned suffn = suff - mycnt; // sum of bins >  t
        if (suff >= (unsigned)r && suffn < (unsigned)r) {  // exactly one thread
            s_rank   = r - (int)suffn;
            s_prefix = (pfx << bits_arr[lvl]) | (unsigned)t;
        }
        __syncthreads();
    }

    const unsigned vkey = s_prefix;   // exact 31-bit abs key of the 32nd largest
    const int eq_need   = s_rank;     // how many ==vkey elements to keep (>=1)

    // ---- final: mask from LDS, write global row + compact (idx,val) lists
#pragma unroll
    for (int c = 0; c < 16; ++c) {
        const int i0 = (c * 256 + t) * 4;
        const float4 v = *(const float4*)(row_s + i0);
        float vv[4] = {v.x, v.y, v.z, v.w};
#pragma unroll
        for (int j = 0; j < 4; ++j) {
            const unsigned k = __float_as_uint(vv[j]) & 0x7FFFFFFFu;
            bool keep = false;
            if (k > vkey) keep = true;
            else if (k == vkey) {
                const int slot = atomicAdd(&s_eq, 1);
                if (slot < eq_need) keep = true;
            }
            if (keep) {
                const int ls = atomicAdd(&s_cnt, 1);
                idx_out[row * KSEL + ls] = i0 + j;
                val_out[row * KSEL + ls] = vv[j];
            } else {
                vv[j] = 0.f;
            }
        }
        float4 o; o.x = vv[0]; o.y = vv[1]; o.z = vv[2]; o.w = vv[3];
        *(float4*)(p + i0) = o;
    }
}

// ---------------------------------------------------------------------------
// Kernel 3: transpose W_dec [1024,16384] -> WdT [16384,1024] (ws scratch)
// ---------------------------------------------------------------------------
__global__ __launch_bounds__(256)
void transpose_wdec(const float* __restrict__ Wd, float* __restrict__ WdT)
{
    __shared__ float tile[32][33];
    const int bx = blockIdx.x;
    const int by = blockIdx.y;
    const int t  = threadIdx.x;
    const int lx = t & 31, ly = t >> 5;
#pragma unroll
    for (int r = 0; r < 32; r += 8)
        tile[ly + r][lx] = Wd[(size_t)(by * 32 + ly + r) * HID + bx * 32 + lx];
    __syncthreads();
#pragma unroll
    for (int r = 0; r < 32; r += 8)
        WdT[(size_t)(bx * 32 + ly + r) * IN_DIM + by * 32 + lx] = tile[lx][ly + r];
}

// ---------------------------------------------------------------------------
// Kernel 4: sparse decode  decoded[b,:] = sum_i val_i * WdT[idx_i,:] + b_dec
// ---------------------------------------------------------------------------
__global__ __launch_bounds__(256)
void decode_rows(const float* __restrict__ WdT, const float* __restrict__ bd,
                 const int* __restrict__ idxs, const float* __restrict__ vals,
                 float* __restrict__ out)
{
    const int row = blockIdx.x;
    const int d   = threadIdx.x * 4;
    float4 acc = *(const float4*)(bd + d);
    for (int i = 0; i < KSEL; ++i) {
        const int   j = idxs[row * KSEL + i];
        const float v = vals[row * KSEL + i];
        const float4 w = *(const float4*)(WdT + (size_t)j * IN_DIM + d);
        acc.x = fmaf(v, w.x, acc.x);
        acc.y = fmaf(v, w.y, acc.y);
        acc.z = fmaf(v, w.z, acc.z);
        acc.w = fmaf(v, w.w, acc.w);
    }
    *(float4*)(out + (size_t)row * IN_DIM + d) = acc;
}

__global__ __launch_bounds__(256)
void decode_rows_noT(const float* __restrict__ Wd, const float* __restrict__ bd,
                     const int* __restrict__ idxs, const float* __restrict__ vals,
                     float* __restrict__ out)
{
    const int row = blockIdx.x;
    const int d0  = threadIdx.x * 4;
    float acc[4];
#pragma unroll
    for (int q = 0; q < 4; ++q) acc[q] = bd[d0 + q];
    for (int i = 0; i < KSEL; ++i) {
        const int   j = idxs[row * KSEL + i];
        const float v = vals[row * KSEL + i];
#pragma unroll
        for (int q = 0; q < 4; ++q)
            acc[q] = fmaf(v, Wd[(size_t)(d0 + q) * HID + j], acc[q]);
    }
#pragma unroll
    for (int q = 0; q < 4; ++q) out[(size_t)row * IN_DIM + d0 + q] = acc[q];
}

// ---------------------------------------------------------------------------
extern "C" void kernel_launch(void* const* d_in, const int* in_sizes, int n_in,
                              void* d_out, int out_size, void* d_ws, size_t ws_size,
                              hipStream_t stream)
{
    const float* x     = (const float*)d_in[0];
    const float* W_enc = (const float*)d_in[1];
    const float* b_enc = (const float*)d_in[2];
    const float* W_dec = (const float*)d_in[3];
    const float* b_dec = (const float*)d_in[4];

    float* out     = (float*)d_out;
    float* sparse  = out;                                // [4096][16384]
    float* decoded = out + (size_t)BATCH * HID;          // [4096][1024]

    // ws layout: [idx list 512KB][val list 512KB][WdT 64MB]
    const size_t list_bytes = (size_t)BATCH * KSEL * 4;
    const size_t wdt_bytes  = (size_t)HID * IN_DIM * 4;
    int*   idx_l = (int*)d_ws;
    float* val_l = (float*)((char*)d_ws + list_bytes);
    float* WdT   = (float*)((char*)d_ws + 2 * list_bytes);
    const bool have_wdt = ws_size >= 2 * list_bytes + wdt_bytes;

    enc_gemm<<<dim3(HID / 128, BATCH / 64), 512, 0, stream>>>(x, W_enc, b_enc, sparse);

    topk_rows<<<BATCH, 256, 0, stream>>>(sparse, idx_l, val_l);

    if (have_wdt) {
        transpose_wdec<<<dim3(HID / 32, IN_DIM / 32), 256, 0, stream>>>(W_dec, WdT);
        decode_rows<<<BATCH, 256, 0, stream>>>(WdT, b_dec, idx_l, val_l, decoded);
    } else {
        decode_rows_noT<<<BATCH, 256, 0, stream>>>(W_dec, b_dec, idx_l, val_l, decoded);
    }
}

// Round 13
// 2014.996 us; speedup vs baseline: 3.0237x; 1.0414x over previous
//
#include <hip/hip_runtime.h>
#include <cstdint>
#include <cstddef>

#define BATCH   4096
#define IN_DIM  1024
#define HID     16384
#define KSEL    32

// ---------------------------------------------------------------------------
// Kernel 1: encoder GEMM  C[B,H] = X[B,D] @ W_enc[H,D]^T + b_enc
// fp32. 64x128 tile, BK=32, 512 threads (8 waves x 8 rows), lane owns 2 cols.
// A is WAVE-UNIFORM -> s_load_dwordx4 into SGPRs (scalar pipe); only B in
// LDS. FMAs in plain C (fmaf).
//
// THIS IS THE PROVEN LOCAL OPTIMUM (r12/r17: 2037/2098us total, enc ~1650us).
// FIVE deviations from this exact structure faulted or spilled:
//   r9/r10: FMA inline asm (VOP2/VOP3)            -> GPU fault
//   r13:    4 cols/lane (+24 VGPR at cap 64)       -> GPU fault
//   r15:    AS4 constant-space A-loads (no asm)    -> 12.8GB scratch spill
//   r16:    LDS double-buffer around the asm block -> GPU fault
//   r5/r7:  bigger acc / vector A-loads            -> scratch spill
// The s_load asm block is BOTH load-bearing (r15: compiler can't scalarize
// A itself) AND brittle (any surrounding-context change faults). DO NOT
// MODIFY enc_gemm — BYTE-IDENTICAL to the twice-passed r12 source. Gap to
// the 874us FMA floor is structural (s->v mov tax ~47%, barrier bubbles
// ~20%, intrinsic b128 bank tax 1.342e8 cyc, identical under two swizzles).
//
// NUMERICS CONTRACT (do not change): per output element, fmaf over k in
// strictly ascending order with a single accumulator, then + bias. Top-k
// rank-32 boundary gaps are ~0.007; any reordering (MFMA bf16x3: absmax
// 4.31, or k-splitting) flips selections vs the np reference. MFMA unusable.
// ---------------------------------------------------------------------------
#define BKK 32

typedef float f32x4_t __attribute__((ext_vector_type(4)));

__global__ __launch_bounds__(512, 8)
void enc_gemm(const float* __restrict__ X, const float* __restrict__ W,
              const float* __restrict__ bias, float* __restrict__ C)
{
    __shared__ __align__(16) float Bs[128 * BKK];   // 16 KB, row-major, swizzled

    const int bn = blockIdx.x;   // HID/128 = 128 (fast dim)
    const int bm = blockIdx.y;   // BATCH/64 = 64
    const int t  = threadIdx.x;  // 0..511
    const int lane = t & 63;
    const int wid  = t >> 6;     // 0..7: wave owns rows bm*64 + wid*8 .. +7

    float acc[8][2];
#pragma unroll
    for (int r = 0; r < 8; ++r) { acc[r][0] = 0.f; acc[r][1] = 0.f; }

    const float* Wb = W + (size_t)(bn * 128) * IN_DIM;

    // Wave-uniform A base (rows bm*64+wid*8 .. +7), forced to SGPR.
    const unsigned rowByte = (unsigned)__builtin_amdgcn_readfirstlane(
        (int)((unsigned)(bm * 64 + wid * 8) * (unsigned)(IN_DIM * 4)));
    const char* aBase = (const char*)X + rowByte;

    const int bswz = lane & 7;   // B-read swizzle key (row&7; (lane+64)&7 same)
    const float* bRow0 = Bs + (size_t)lane * BKK;        // col = lane
    const float* bRow1 = Bs + (size_t)(lane + 64) * BKK; // col = lane+64

    for (int k0 = 0; k0 < IN_DIM; k0 += BKK) {
        // ---- stage 128x32 B tile: 2 x 16B per thread (512 threads).
        // LDS slot s (16B) holds row m = s>>3, global chunk (s&7)^(m&7).
        // Read of logical chunk kq of row m is at physical chunk kq^(m&7):
        // lanes 0..7 read 8 distinct chunks. Lane-contiguous LDS dst
        // satisfies wave-uniform-base + lane*16; each 8-lane group reads
        // one contiguous (permuted) 128B of global -> fully coalesced.
#pragma unroll
        for (int q = 0; q < 2; ++q) {
            const int s  = q * 512 + t;           // 0..1023
            const int m  = s >> 3;                // 0..127
            const int gc = (s & 7) ^ (m & 7);
            __builtin_amdgcn_global_load_lds(
                (const __attribute__((address_space(1))) void*)(Wb + (size_t)m * IN_DIM + k0 + gc * 4),
                (__attribute__((address_space(3))) void*)(Bs + s * 4), 16, 0, 0);
        }
        __syncthreads();   // drains vmcnt (global_load_lds) before reads

        // ---- compute: 8 groups of 4 consecutive k.
#pragma unroll
        for (int kq = 0; kq < 8; ++kq) {
            const float4 b0 = *(const float4*)(bRow0 + ((kq ^ bswz) * 4));
            const float4 b1 = *(const float4*)(bRow1 + ((kq ^ bswz) * 4));

            // A: 8 rows x 4 k into SGPRs. One volatile asm block per kq:
            // bounded SGPR live range (32), cannot be hoisted across kq.
            // EXACT r8/r12 block — do not alter (pressure-fragility).
            const char* apq = aBase + (size_t)(k0 + kq * 4) * 4;
            f32x4_t a0, a1, a2, a3, a4, a5, a6, a7;
            asm volatile(
                "s_load_dwordx4 %[r0], %[ap], 0x0\n\t"
                "s_load_dwordx4 %[r1], %[ap], 0x1000\n\t"
                "s_load_dwordx4 %[r2], %[ap], 0x2000\n\t"
                "s_load_dwordx4 %[r3], %[ap], 0x3000\n\t"
                "s_load_dwordx4 %[r4], %[ap], 0x4000\n\t"
                "s_load_dwordx4 %[r5], %[ap], 0x5000\n\t"
                "s_load_dwordx4 %[r6], %[ap], 0x6000\n\t"
                "s_load_dwordx4 %[r7], %[ap], 0x7000\n\t"
                "s_waitcnt lgkmcnt(0)"
                : [r0]"=s"(a0), [r1]"=s"(a1), [r2]"=s"(a2), [r3]"=s"(a3),
                  [r4]"=s"(a4), [r5]"=s"(a5), [r6]"=s"(a6), [r7]"=s"(a7)
                : [ap]"s"(apq));

            // k ascending per output, x->y->z->w: bit-identical chain.
            // Plain fmaf (NO inline asm here — r9/r10 lesson).
#define ROW_FMA(AV, R)                                   \
            acc[R][0] = fmaf(AV.x, b0.x, acc[R][0]);     \
            acc[R][1] = fmaf(AV.x, b1.x, acc[R][1]);     \
            acc[R][0] = fmaf(AV.y, b0.y, acc[R][0]);     \
            acc[R][1] = fmaf(AV.y, b1.y, acc[R][1]);     \
            acc[R][0] = fmaf(AV.z, b0.z, acc[R][0]);     \
            acc[R][1] = fmaf(AV.z, b1.z, acc[R][1]);     \
            acc[R][0] = fmaf(AV.w, b0.w, acc[R][0]);     \
            acc[R][1] = fmaf(AV.w, b1.w, acc[R][1]);
            ROW_FMA(a0, 0) ROW_FMA(a1, 1) ROW_FMA(a2, 2) ROW_FMA(a3, 3)
            ROW_FMA(a4, 4) ROW_FMA(a5, 5) ROW_FMA(a6, 6) ROW_FMA(a7, 7)
#undef ROW_FMA
        }
        __syncthreads();
    }

    const int r0 = bm * 64 + wid * 8;
    const int c0 = bn * 128 + lane;
    const float bv0 = bias[c0];
    const float bv1 = bias[c0 + 64];
#pragma unroll
    for (int r = 0; r < 8; ++r) {
        C[(size_t)(r0 + r) * HID + c0]      = acc[r][0] + bv0;
        C[(size_t)(r0 + r) * HID + c0 + 64] = acc[r][1] + bv1;
    }
}

// ---------------------------------------------------------------------------
// Kernel 2 (v5): per-row exact top-32 by |value|, 4-level radix select on
// abs bit pattern. Row cached in LDS (64 KB) -> global traffic = 1 read +
// 1 write. r18 NEW: candidate compaction — after lvl0 picks the boundary
// EXPONENT bin, only elements in that bin matter for levels 1-3. The lvl1
// full scan now also appends matching indices to a 512-entry LDS list;
// levels 2-3 scan the list (~30-80 elems for N(0,1.4) data) instead of the
// full 16384 row. Full 64KB passes: 5 -> 3. Overflow (>512 cands) falls
// back to the original full-scan path — selection math identical either
// way (same vkey/eq_need/keep-set => bit-identical output).
// Levels: bits 30:23 (256), 22:15 (256), 14:7 (256), 6:0 (128).
// LDS: 64K row + 8.2K h8 + 1K hist + 2K cand ~= 76.9KB -> 2 blocks/CU.
// ---------------------------------------------------------------------------
#define CAND_CAP 512

__global__ __launch_bounds__(256)
void topk_rows(float* __restrict__ E, int* __restrict__ idx_out,
               float* __restrict__ val_out)
{
    const int row = blockIdx.x;
    float* p = E + (size_t)row * HID;
    const int t    = threadIdx.x;
    const int lane = t & 63;
    const int wid  = t >> 6;

    __shared__ __align__(16) float row_s[HID];   // 64 KB row cache
    __shared__ unsigned h8[8][257];              // lvl-0 privatized hists
    __shared__ unsigned hist[256];
    __shared__ unsigned wsum[4];
    __shared__ int cand[CAND_CAP];               // lvl-0-bin candidate idxs
    __shared__ int s_ncand;
    __shared__ unsigned s_prefix;
    __shared__ int s_rank, s_eq, s_cnt;

    // async-load the whole row into LDS (lane-contiguous 16B chunks)
#pragma unroll
    for (int c = 0; c < 16; ++c) {
        const int s = c * 256 + t;
        __builtin_amdgcn_global_load_lds(
            (const __attribute__((address_space(1))) void*)(p + (size_t)s * 4),
            (__attribute__((address_space(3))) void*)(row_s + s * 4), 16, 0, 0);
    }
    for (int i = t; i < 8 * 257; i += 256) ((unsigned*)h8)[i] = 0u;
    if (t == 0) { s_rank = KSEL; s_prefix = 0u; s_eq = 0; s_cnt = 0; s_ncand = 0; }
    __syncthreads();

    // ---- level 0: exponent-byte histogram into 8 privatized copies
    unsigned* myh = h8[t & 7];
#pragma unroll
    for (int c = 0; c < 16; ++c) {
        const float4 v = *(const float4*)(row_s + (c * 256 + t) * 4);
        const float vv[4] = {v.x, v.y, v.z, v.w};
#pragma unroll
        for (int j = 0; j < 4; ++j)
            atomicAdd(&myh[(__float_as_uint(vv[j]) & 0x7FFFFFFFu) >> 23], 1u);
    }
    __syncthreads();

    const int psh_arr[4]  = {31, 23, 15, 7};
    const int sh_arr[4]   = {23, 15, 7, 0};
    const unsigned msk[4] = {255u, 255u, 255u, 127u};
    const int bits_arr[4] = {8, 8, 8, 7};

#pragma unroll
    for (int lvl = 0; lvl < 4; ++lvl) {
        const int r = s_rank;
        const unsigned pfx = s_prefix;

        unsigned mycnt;
        if (lvl == 0) {
            unsigned m = 0;
#pragma unroll
            for (int c = 0; c < 8; ++c) m += h8[c][t];
            mycnt = m;                       // own bin, no barrier needed
        } else {
            hist[t] = 0u;
            __syncthreads();
            const int psh = psh_arr[lvl];
            const int sh  = sh_arr[lvl];
            if (lvl == 1) {
                // full scan + histogram + COMPACT candidates (lvl0-bin members)
#pragma unroll
                for (int c = 0; c < 16; ++c) {
                    const int i0 = (c * 256 + t) * 4;
                    const float4 v = *(const float4*)(row_s + i0);
                    const float vv[4] = {v.x, v.y, v.z, v.w};
#pragma unroll
                    for (int j = 0; j < 4; ++j) {
                        const unsigned k = __float_as_uint(vv[j]) & 0x7FFFFFFFu;
                        if ((k >> psh) == pfx) {
                            atomicAdd(&hist[(k >> sh) & msk[lvl]], 1u);
                            const int cs = atomicAdd(&s_ncand, 1);
                            if (cs < CAND_CAP) cand[cs] = i0 + j;
                        }
                    }
                }
            } else if (s_ncand <= CAND_CAP) {
                // candidate-list scan (~tens of elements): few iterations
                const int n = s_ncand;
                for (int i = t; i < n; i += 256) {
                    const unsigned k = __float_as_uint(row_s[cand[i]]) & 0x7FFFFFFFu;
                    if ((k >> psh) == pfx)
                        atomicAdd(&hist[(k >> sh) & msk[lvl]], 1u);
                }
            } else {
                // overflow fallback: original full scan (same math)
#pragma unroll
                for (int c = 0; c < 16; ++c) {
                    const float4 v = *(const float4*)(row_s + (c * 256 + t) * 4);
                    const float vv[4] = {v.x, v.y, v.z, v.w};
#pragma unroll
                    for (int j = 0; j < 4; ++j) {
                        const unsigned k = __float_as_uint(vv[j]) & 0x7FFFFFFFu;
                        if ((k >> psh) == pfx)
                            atomicAdd(&hist[(k >> sh) & msk[lvl]], 1u);
                    }
                }
            }
            __syncthreads();
            mycnt = hist[t];
        }

        // wave-level inclusive suffix scan of bin counts (bin index = t)
        unsigned sv = mycnt;
#pragma unroll
        for (int off = 1; off < 64; off <<= 1) {
            const unsigned u = __shfl_down(sv, off, 64);
            sv += (lane + off < 64) ? u : 0u;
        }
        if (lane == 0) wsum[wid] = sv;       // this wave's 64-bin total
        __syncthreads();
        unsigned above = 0;
        for (int ww = wid + 1; ww < 4; ++ww) above += wsum[ww];
        const unsigned suff  = sv + above;   // sum of bins >= t
        const unsigned suffn = suff - mycnt; // sum of bins >  t
        if (suff >= (unsigned)r && suffn < (unsigned)r) {  // exactly one thread
            s_rank   = r - (int)suffn;
            s_prefix = (pfx << bits_arr[lvl]) | (unsigned)t;
        }
        __syncthreads();
    }

    const unsigned vkey = s_prefix;   // exact 31-bit abs key of the 32nd largest
    const int eq_need   = s_rank;     // how many ==vkey elements to keep (>=1)

    // ---- final: mask from LDS, write global row + compact (idx,val) lists
#pragma unroll
    for (int c = 0; c < 16; ++c) {
        const int i0 = (c * 256 + t) * 4;
        const float4 v = *(const float4*)(row_s + i0);
        float vv[4] = {v.x, v.y, v.z, v.w};
#pragma unroll
        for (int j = 0; j < 4; ++j) {
            const unsigned k = __float_as_uint(vv[j]) & 0x7FFFFFFFu;
            bool keep = false;
            if (k > vkey) keep = true;
            else if (k == vkey) {
                const int slot = atomicAdd(&s_eq, 1);
                if (slot < eq_need) keep = true;
            }
            if (keep) {
                const int ls = atomicAdd(&s_cnt, 1);
                idx_out[row * KSEL + ls] = i0 + j;
                val_out[row * KSEL + ls] = vv[j];
            } else {
                vv[j] = 0.f;
            }
        }
        float4 o; o.x = vv[0]; o.y = vv[1]; o.z = vv[2]; o.w = vv[3];
        *(float4*)(p + i0) = o;
    }
}

// ---------------------------------------------------------------------------
// Kernel 3: transpose W_dec [1024,16384] -> WdT [16384,1024] (ws scratch)
// ---------------------------------------------------------------------------
__global__ __launch_bounds__(256)
void transpose_wdec(const float* __restrict__ Wd, float* __restrict__ WdT)
{
    __shared__ float tile[32][33];
    const int bx = blockIdx.x;
    const int by = blockIdx.y;
    const int t  = threadIdx.x;
    const int lx = t & 31, ly = t >> 5;
#pragma unroll
    for (int r = 0; r < 32; r += 8)
        tile[ly + r][lx] = Wd[(size_t)(by * 32 + ly + r) * HID + bx * 32 + lx];
    __syncthreads();
#pragma unroll
    for (int r = 0; r < 32; r += 8)
        WdT[(size_t)(bx * 32 + ly + r) * IN_DIM + by * 32 + lx] = tile[lx][ly + r];
}

// ---------------------------------------------------------------------------
// Kernel 4: sparse decode  decoded[b,:] = sum_i val_i * WdT[idx_i,:] + b_dec
// ---------------------------------------------------------------------------
__global__ __launch_bounds__(256)
void decode_rows(const float* __restrict__ WdT, const float* __restrict__ bd,
                 const int* __restrict__ idxs, const float* __restrict__ vals,
                 float* __restrict__ out)
{
    const int row = blockIdx.x;
    const int d   = threadIdx.x * 4;
    float4 acc = *(const float4*)(bd + d);
    for (int i = 0; i < KSEL; ++i) {
        const int   j = idxs[row * KSEL + i];
        const float v = vals[row * KSEL + i];
        const float4 w = *(const float4*)(WdT + (size_t)j * IN_DIM + d);
        acc.x = fmaf(v, w.x, acc.x);
        acc.y = fmaf(v, w.y, acc.y);
        acc.z = fmaf(v, w.z, acc.z);
        acc.w = fmaf(v, w.w, acc.w);
    }
    *(float4*)(out + (size_t)row * IN_DIM + d) = acc;
}

__global__ __launch_bounds__(256)
void decode_rows_noT(const float* __restrict__ Wd, const float* __restrict__ bd,
                     const int* __restrict__ idxs, const float* __restrict__ vals,
                     float* __restrict__ out)
{
    const int row = blockIdx.x;
    const int d0  = threadIdx.x * 4;
    float acc[4];
#pragma unroll
    for (int q = 0; q < 4; ++q) acc[q] = bd[d0 + q];
    for (int i = 0; i < KSEL; ++i) {
        const int   j = idxs[row * KSEL + i];
        const float v = vals[row * KSEL + i];
#pragma unroll
        for (int q = 0; q < 4; ++q)
            acc[q] = fmaf(v, Wd[(size_t)(d0 + q) * HID + j], acc[q]);
    }
#pragma unroll
    for (int q = 0; q < 4; ++q) out[(size_t)row * IN_DIM + d0 + q] = acc[q];
}

// ---------------------------------------------------------------------------
extern "C" void kernel_launch(void* const* d_in, const int* in_sizes, int n_in,
                              void* d_out, int out_size, void* d_ws, size_t ws_size,
                              hipStream_t stream)
{
    const float* x     = (const float*)d_in[0];
    const float* W_enc = (const float*)d_in[1];
    const float* b_enc = (const float*)d_in[2];
    const float* W_dec = (const float*)d_in[3];
    const float* b_dec = (const float*)d_in[4];

    float* out     = (float*)d_out;
    float* sparse  = out;                                // [4096][16384]
    float* decoded = out + (size_t)BATCH * HID;          // [4096][1024]

    // ws layout: [idx list 512KB][val list 512KB][WdT 64MB]
    const size_t list_bytes = (size_t)BATCH * KSEL * 4;
    const size_t wdt_bytes  = (size_t)HID * IN_DIM * 4;
    int*   idx_l = (int*)d_ws;
    float* val_l = (float*)((char*)d_ws + list_bytes);
    float* WdT   = (float*)((char*)d_ws + 2 * list_bytes);
    const bool have_wdt = ws_size >= 2 * list_bytes + wdt_bytes;

    enc_gemm<<<dim3(HID / 128, BATCH / 64), 512, 0, stream>>>(x, W_enc, b_enc, sparse);

    topk_rows<<<BATCH, 256, 0, stream>>>(sparse, idx_l, val_l);

    if (have_wdt) {
        transpose_wdec<<<dim3(HID / 32, IN_DIM / 32), 256, 0, stream>>>(W_dec, WdT);
        decode_rows<<<BATCH, 256, 0, stream>>>(WdT, b_dec, idx_l, val_l, decoded);
    } else {
        decode_rows_noT<<<BATCH, 256, 0, stream>>>(W_dec, b_dec, idx_l, val_l, decoded);
    }
}